// Round 4
// baseline (63.855 us; speedup 1.0000x reference)
//
#include <hip/hip_runtime.h>

// HighOrderActivationB: per (b,g) task over r=3 inputs.
//   sort |a| ascending (stable), coef = diffs of sorted |a|,
//   idx[j] = 13 + sum_{k>=j} sgn[p_k]*3^{p_k},
//   out[d] = sum_j coef[j] * params[g, idx[j], d]
// Memory-bound: ~50MB X read + ~134MB out write; params (0.88MB) L2-resident.

#define B_BATCH 4096
#define N_GROUPS 1024
#define ARITY 3
#define N_TERMS 27
#define OUT_DIM 8

__global__ __launch_bounds__(256)
void hoa_kernel(const float* __restrict__ X,
                const float* __restrict__ P,
                float* __restrict__ out) {
    const int tid = blockIdx.x * blockDim.x + threadIdx.x;   // b*N_GROUPS + g
    const int g = tid & (N_GROUPS - 1);

    // ---- load 3 inputs (lanes read contiguous 12B chunks; wave covers 768B) ----
    const float* xp = X + (size_t)tid * ARITY;
    float a0 = xp[0], a1 = xp[1], a2 = xp[2];

    float m0 = fabsf(a0), m1 = fabsf(a1), m2 = fabsf(a2);
    // term = sign * 3^original_index  (sign: a>=0 -> +1)
    int t0 = (a0 >= 0.0f) ? 1 : -1;
    int t1 = (a1 >= 0.0f) ? 3 : -3;
    int t2 = (a2 >= 0.0f) ? 9 : -9;

    // ---- stable 3-element ascending sort by magnitude (strict > = stable) ----
    if (m0 > m1) { float tm = m0; m0 = m1; m1 = tm; int tt = t0; t0 = t1; t1 = tt; }
    if (m1 > m2) { float tm = m1; m1 = m2; m2 = tm; int tt = t1; t1 = t2; t2 = tt; }
    if (m0 > m1) { float tm = m0; m0 = m1; m1 = tm; int tt = t0; t0 = t1; t1 = tt; }

    const float c0 = m0;
    const float c1 = m1 - m0;
    const float c2 = m2 - m1;

    // suffix sums of terms -> indices into [0,26]
    const int i2 = 13 + t2;
    const int i1 = i2 + t1;
    const int i0 = i1 + t0;

    // ---- gather 3 rows of 8 floats from this group's param table (L2-hit) ----
    const float* pg = P + (size_t)g * (N_TERMS * OUT_DIM);
    const float4* r0 = (const float4*)(pg + i0 * OUT_DIM);
    const float4* r1 = (const float4*)(pg + i1 * OUT_DIM);
    const float4* r2 = (const float4*)(pg + i2 * OUT_DIM);
    float4 g0a = r0[0], g0b = r0[1];
    float4 g1a = r1[0], g1b = r1[1];
    float4 g2a = r2[0], g2b = r2[1];

    float4 oa, ob;
    oa.x = c0 * g0a.x + c1 * g1a.x + c2 * g2a.x;
    oa.y = c0 * g0a.y + c1 * g1a.y + c2 * g2a.y;
    oa.z = c0 * g0a.z + c1 * g1a.z + c2 * g2a.z;
    oa.w = c0 * g0a.w + c1 * g1a.w + c2 * g2a.w;
    ob.x = c0 * g0b.x + c1 * g1b.x + c2 * g2b.x;
    ob.y = c0 * g0b.y + c1 * g1b.y + c2 * g2b.y;
    ob.z = c0 * g0b.z + c1 * g1b.z + c2 * g2b.z;
    ob.w = c0 * g0b.w + c1 * g1b.w + c2 * g2b.w;

    // ---- coalesced store: 2x float4 per lane ----
    float4* op = (float4*)(out + (size_t)tid * OUT_DIM);
    op[0] = oa;
    op[1] = ob;
}

extern "C" void kernel_launch(void* const* d_in, const int* in_sizes, int n_in,
                              void* d_out, int out_size, void* d_ws, size_t ws_size,
                              hipStream_t stream) {
    const float* X = (const float*)d_in[0];
    const float* P = (const float*)d_in[1];
    float* out = (float*)d_out;

    const int total = B_BATCH * N_GROUPS;          // 4,194,304 threads
    const int block = 256;
    const int grid = total / block;                // 16384 blocks
    hoa_kernel<<<grid, block, 0, stream>>>(X, P, out);
}